// Round 9
// baseline (7703.674 us; speedup 1.0000x reference)
//
#include <hip/hip_runtime.h>
#include <hip/hip_bf16.h>

#define T_TOTAL 1024
#define BATCH   64
#define HID     512

__device__ __forceinline__ float fast_sigmoid(float x) {
    return 1.f / (1.f + __expf(-x));
}
__device__ __forceinline__ float fast_tanh(float x) {
    float ax = fabsf(x);
    float e  = __expf(-2.f * ax);
    float t  = (1.f - e) / (1.f + e);
    return copysignf(t, x);
}

// ---------------------------------------------------------------------------
// GEMM: C[m,n] = sum_k A[rowg(m),k] * W[n,k] + bias[n]
// A row-major [*, K], W row-major [N, K] (i.e. computes A @ W^T + bias).
// ---------------------------------------------------------------------------
template<int BM, int BN, int TM, int TN>
__global__ __launch_bounds__(256, 2)
void gemm_bt_k(const float* __restrict__ A, const float* __restrict__ W,
               const float* __restrict__ bias, float* __restrict__ C,
               int K, int T, int Tc, int t0, int N)
{
    constexpr int BK = 16;
    constexpr int WSTR = BN + (BN / 32) * 4;
    static_assert(BM / TM == 16 && BN / TN == 16, "256 threads required");
    __shared__ float As[BK][BM + 4];
    __shared__ float Ws[BK][WSTR];

    const int tid = threadIdx.x;
    const int tx  = tid & 15;
    const int ty  = tid >> 4;
    const int m0  = blockIdx.y * BM;
    const int n0  = blockIdx.x * BN;
    const int nA  = tx * TN;
    const int nsw = nA + ((nA >> 5) << 2);

    float acc[TM][TN];
#pragma unroll
    for (int i = 0; i < TM; ++i)
#pragma unroll
        for (int j = 0; j < TN; ++j) acc[i][j] = 0.f;

    for (int k0 = 0; k0 < K; k0 += BK) {
#pragma unroll
        for (int i = 0; i < (BM * BK) / 1024; ++i) {
            int id = tid + (i << 8);
            int m  = id >> 2;
            int kq = (id & 3) << 2;
            int mloc = m0 + m;
            int rowg = (mloc / Tc) * T + t0 + (mloc % Tc);
            const float4 v = *reinterpret_cast<const float4*>(A + (size_t)rowg * K + k0 + kq);
            As[kq + 0][m] = v.x; As[kq + 1][m] = v.y;
            As[kq + 2][m] = v.z; As[kq + 3][m] = v.w;
        }
#pragma unroll
        for (int i = 0; i < (BN * BK) / 1024; ++i) {
            int id = tid + (i << 8);
            int n  = id >> 2;
            int kq = (id & 3) << 2;
            const float4 v = *reinterpret_cast<const float4*>(W + (size_t)(n0 + n) * K + k0 + kq);
            int np = n + ((n >> 5) << 2);
            Ws[kq + 0][np] = v.x; Ws[kq + 1][np] = v.y;
            Ws[kq + 2][np] = v.z; Ws[kq + 3][np] = v.w;
        }
        __syncthreads();
#pragma unroll
        for (int k = 0; k < BK; ++k) {
            float a[TM], b[TN];
#pragma unroll
            for (int i = 0; i < TM; i += 4)
                *reinterpret_cast<float4*>(&a[i]) =
                    *reinterpret_cast<const float4*>(&As[k][ty * TM + i]);
#pragma unroll
            for (int j = 0; j < TN; j += 4)
                *reinterpret_cast<float4*>(&b[j]) =
                    *reinterpret_cast<const float4*>(&Ws[k][nsw + j]);
#pragma unroll
            for (int i = 0; i < TM; ++i)
#pragma unroll
                for (int j = 0; j < TN; ++j)
                    acc[i][j] = fmaf(a[i], b[j], acc[i][j]);
        }
        __syncthreads();
    }
#pragma unroll
    for (int i = 0; i < TM; ++i) {
        const size_t crow = (size_t)(m0 + ty * TM + i) * N + n0 + nA;
#pragma unroll
        for (int j = 0; j < TN; j += 4) {
            float4 bv = *reinterpret_cast<const float4*>(bias + n0 + nA + j);
            float4 v;
            v.x = acc[i][j + 0] + bv.x; v.y = acc[i][j + 1] + bv.y;
            v.z = acc[i][j + 2] + bv.z; v.w = acc[i][j + 3] + bv.w;
            *reinterpret_cast<float4*>(C + crow + j) = v;
        }
    }
}

// ---------------------------------------------------------------------------
// Persistent GRU scan (one T-chunk of one layer) — R9.
// R8 skeleton (32 groups x 8 blocks x 512 thr; register-resident weights;
// part-LDS reduce; tight s_sleep(1); contiguous publish) + two changes:
//   1. COUNTER-HINT poll: producers bump cnt[grp] (2 adds/block/step, after
//      s_waitcnt vmcnt(0) orders them behind the data stores). Consumer
//      tid0 polls ONE word (vs R8: 8 blocks x 1024 atomic loads/round on
//      32 lines = the detect-latency storm), then all threads do ONE
//      tag-verified bulk load. Tags stay the correctness backstop — the
//      hint can only cause a rare extra tag round, never wrong data.
//      Counter is monotonic across all 8 dispatches (cntbase per launch,
//      single memset per kernel_launch); replay-safe.
//   2. MERGED reduce+gates: tid<128 sums all 3 gates' 8 partials straight
//      from part[] (identical FP order -> bit-identical result), killing
//      barrier #3 and the hg_red round trip.
// ---------------------------------------------------------------------------
__global__ __launch_bounds__(512, 2)
void gru_scan(const float* __restrict__ xg,    // chunk-local [64][Tc][1536]
              const float* __restrict__ w_hh,  // [1536][512]
              const float* __restrict__ b_hh,  // [1536]
              float* __restrict__ y,           // [64][1024][512]
              unsigned long long* __restrict__ hbuf, // [32 grp][2 slot][2 b][512]
              unsigned int* __restrict__ cnt,  // [32 grp] stride 32 u32
              int t0, int Tc, int tagbase, unsigned int cntbase)
{
    const int tid = threadIdx.x;
    const int grp = blockIdx.x & 31;      // 8 blocks of a group: same XCD
    const int os  = blockIdx.x >> 5;      // output slice 0..7
    const int D0  = os << 6;              // 64 h-dims per block
    const int d   = tid & 63;
    const int kc  = tid >> 6;             // K-chunk 0..7 (64 K each)
    const int bg  = grp << 1;             // 2 batch rows per group

    constexpr int HP = 528;               // h row pad (16B-aligned)
    __shared__ float h_lds[2][2 * HP];    // [slot][b][D] flat
    __shared__ float part[8 * 392];       // [kc][g*128 + b*64 + d] (384 used)

    // persistent weights: w4[g][j] = w_hh[g*512+D0+d][kc*64 + 4j ..]
    float4 w4[3][16];
#pragma unroll
    for (int g = 0; g < 3; ++g) {
        const float* wr = w_hh + (size_t)(g * 512 + D0 + d) * 512 + kc * 64;
#pragma unroll
        for (int j = 0; j < 16; ++j)
            w4[g][j] = *reinterpret_cast<const float4*>(wr + (j << 2));
    }
    // gate-thread biases (merged reduce): all 3 gates for dim D0+(tid&63)
    float bias_r = 0.f, bias_z = 0.f, bias_n = 0.f;
    if (tid < 128) {
        bias_r = b_hh[       D0 + (tid & 63)];
        bias_z = b_hh[ 512 + D0 + (tid & 63)];
        bias_n = b_hh[1024 + D0 + (tid & 63)];
    }
    const int b_loc = tid >> 6;           // gate threads (tid<128): row 0..1
    unsigned int* cptr = cnt + grp * 32;

    for (int tl = 0; tl < Tc; ++tl) {
        const int tg = t0 + tl;
        float* hl = h_lds[tl & 1];

        // gate threads prefetch this step's xg early (hidden behind poll)
        float xr = 0.f, xz = 0.f, xn = 0.f;
        if (tid < 128) {
            const size_t rowo = ((size_t)(bg + b_loc) * Tc + tl) * 1536 + D0 + d;
            xr = xg[rowo];
            xz = xg[rowo + 512];
            xn = xg[rowo + 1024];
        }

        // stage h_{t-1}[2][512] into LDS
        if (tg == 0) {
#pragma unroll
            for (int i = 0; i < 2; ++i) {
                int idx = tid + (i << 9);
                hl[(idx >> 9) * HP + (idx & 511)] = 0.f;
            }
        } else {
            // counter-hint: ONE thread polls ONE word (16 adds/step/group)
            if (tid == 0) {
                const unsigned int tgt = cntbase + 16u * (unsigned int)tl;
                while (__hip_atomic_load(cptr, __ATOMIC_RELAXED,
                                         __HIP_MEMORY_SCOPE_AGENT) < tgt) {
                    __builtin_amdgcn_s_sleep(1);
                }
            }
            __syncthreads();   // barrier #0: hint passed

            // tag-verified bulk load (normally 1 round; backstop loop)
            const unsigned long long* hsrc =
                hbuf + (size_t)(grp * 2 + ((tg - 1) & 1)) * 1024;
            const unsigned int tagexp = (unsigned int)(tagbase + tl - 1);
            unsigned long long v[2];
            unsigned int pend = 0x3u;
            while (pend) {
#pragma unroll
                for (int i = 0; i < 2; ++i)
                    if (pend & (1u << i))
                        v[i] = __hip_atomic_load(hsrc + tid + (i << 9),
                                __ATOMIC_RELAXED, __HIP_MEMORY_SCOPE_AGENT);
#pragma unroll
                for (int i = 0; i < 2; ++i)
                    if ((pend & (1u << i)) &&
                        (unsigned int)(v[i] >> 32) == tagexp) {
                        int idx = tid + (i << 9);
                        union { unsigned int u; float f; } cv;
                        cv.u = (unsigned int)v[i];
                        hl[(idx >> 9) * HP + (idx & 511)] = cv.f;
                        pend &= ~(1u << i);
                    }
                if (pend) __builtin_amdgcn_s_sleep(1);
            }
        }
        __syncthreads();   // barrier #1: h_{t-1} staged

        // register MAC over this thread's 64-wide K chunk; kc wave-uniform
        // -> both b128 loads per j are full-wave broadcasts.
        float acc[3][2];
#pragma unroll
        for (int g = 0; g < 3; ++g) { acc[g][0] = 0.f; acc[g][1] = 0.f; }
        const float* hb_base = hl + kc * 64;
#pragma unroll
        for (int j = 0; j < 16; ++j) {
            const float4 h0 = *reinterpret_cast<const float4*>(hb_base + (j << 2));
            const float4 h1 = *reinterpret_cast<const float4*>(hb_base + HP + (j << 2));
#pragma unroll
            for (int g = 0; g < 3; ++g) {
                const float4 wv = w4[g][j];
                acc[g][0] = fmaf(wv.x, h0.x, acc[g][0]);
                acc[g][0] = fmaf(wv.y, h0.y, acc[g][0]);
                acc[g][0] = fmaf(wv.z, h0.z, acc[g][0]);
                acc[g][0] = fmaf(wv.w, h0.w, acc[g][0]);
                acc[g][1] = fmaf(wv.x, h1.x, acc[g][1]);
                acc[g][1] = fmaf(wv.y, h1.y, acc[g][1]);
                acc[g][1] = fmaf(wv.z, h1.z, acc[g][1]);
                acc[g][1] = fmaf(wv.w, h1.w, acc[g][1]);
            }
        }
        {
            float* pp = part + kc * 392 + d;
#pragma unroll
            for (int g = 0; g < 3; ++g) {
                pp[g * 128]      = acc[g][0];
                pp[g * 128 + 64] = acc[g][1];
            }
        }
        __syncthreads();   // barrier #2: partials complete

        // merged reduce + gates + tagged publish + counter bump.
        // output o = g*128 + tid (b=tid>>6, d=tid&63); FP order identical
        // to R8's two-stage reduce (bias first, then q ascending).
        if (tid < 128) {
            float sr = bias_r, sz = bias_z, sn = bias_n;
#pragma unroll
            for (int q = 0; q < 8; ++q) {
                sr += part[q * 392 +       tid];
                sz += part[q * 392 + 128 + tid];
                sn += part[q * 392 + 256 + tid];
            }
            const int D = D0 + d;
            const float hp = hl[b_loc * HP + D];
            const float r  = fast_sigmoid(xr + sr);
            const float z  = fast_sigmoid(xz + sz);
            const float nv = fast_tanh(xn + r * sn);
            const float h  = (1.f - z) * nv + z * hp;
            union { float f; unsigned int u; } cv; cv.f = h;
            const unsigned long long pk =
                ((unsigned long long)(unsigned int)(tagbase + tl) << 32) | cv.u;
            unsigned long long* hdst =
                hbuf + (size_t)(grp * 2 + (tg & 1)) * 1024 + b_loc * 512 + D;
            __hip_atomic_store(hdst, pk, __ATOMIC_RELAXED,
                               __HIP_MEMORY_SCOPE_AGENT);
            y[((size_t)(bg + b_loc) * T_TOTAL + tg) * HID + D] = h;
            // order the hint behind the data stores, then bump (lane 0 of
            // each publisher wave -> 2 adds/block, 16/group/step)
            __builtin_amdgcn_sched_barrier(0);
            __builtin_amdgcn_s_waitcnt(0x0F70);   // vmcnt(0) only
            __builtin_amdgcn_sched_barrier(0);
            if ((tid & 63) == 0)
                __hip_atomic_fetch_add(cptr, 1u, __ATOMIC_RELAXED,
                                       __HIP_MEMORY_SCOPE_AGENT);
        }
        // no trailing barrier: next iter stages into the other h_lds slot;
        // part(t+1) writes happen only after barrier#1(t+1).
    }
}

// ---------------------------------------------------------------------------
extern "C" void kernel_launch(void* const* d_in, const int* in_sizes, int n_in,
                              void* d_out, int out_size, void* d_ws, size_t ws_size,
                              hipStream_t stream)
{
    const float* x       = (const float*)d_in[0];
    const float* w_ih[2] = {(const float*)d_in[1], (const float*)d_in[5]};
    const float* w_hh[2] = {(const float*)d_in[2], (const float*)d_in[6]};
    const float* b_ih[2] = {(const float*)d_in[3], (const float*)d_in[7]};
    const float* b_hh[2] = {(const float*)d_in[4], (const float*)d_in[8]};
    const float* fc_w    = (const float*)d_in[9];
    const float* fc_b    = (const float*)d_in[10];
    float* out = (float*)d_out;

    const size_t Y_BYTES = (size_t)BATCH * T_TOTAL * HID * 4;   // 128 MiB
    const size_t H_BYTES = (size_t)32 * 2 * 2 * 512 * 8;        // 512 KiB (u64)
    const size_t C_BYTES = (size_t)32 * 32 * 4;                 // 4 KiB counters
    int Tc = 256;
    while (Tc > 32) {
        size_t need = (size_t)BATCH * Tc * 1536 * 4 + Y_BYTES + H_BYTES + C_BYTES;
        if (need <= ws_size) break;
        Tc >>= 1;
    }

    char* p = (char*)d_ws;
    float* xg_buf = (float*)p;                 p += (size_t)BATCH * Tc * 1536 * 4;
    float* y_buf  = (float*)p;                 p += Y_BYTES;
    unsigned long long* hbuf = (unsigned long long*)p; p += H_BYTES;
    unsigned int* cnt = (unsigned int*)p;

    // one memset per call; counters are monotonic across the 8 dispatches
    hipMemsetAsync(cnt, 0, C_BYTES, stream);

    const int nchunks = T_TOTAL / Tc;
    for (int L = 0; L < 2; ++L) {
        const float* A = L ? y_buf : x;
        const int K    = L ? HID : 64;
        for (int c = 0; c < nchunks; ++c) {
            dim3 g1(1536 / 128, (BATCH * Tc) / 128);
            gemm_bt_k<128, 128, 8, 8><<<g1, 256, 0, stream>>>(
                A, w_ih[L], b_ih[L], xg_buf, K, T_TOTAL, Tc, c * Tc, 1536);
            const int epoch = L * nchunks + c;
            gru_scan<<<256, 512, 0, stream>>>(
                xg_buf, w_hh[L], b_hh[L], y_buf, hbuf, cnt,
                c * Tc, Tc, (L << 11) + c * Tc,
                (unsigned int)(epoch * 16 * Tc));
        }
    }
    dim3 g2(64 / 64, (BATCH * T_TOTAL) / 128);
    gemm_bt_k<128, 64, 8, 4><<<g2, 256, 0, stream>>>(
        y_buf, fc_w, fc_b, out, HID, BATCH * T_TOTAL, BATCH * T_TOTAL, 0, 64);
}

// Round 10
// 6390.509 us; speedup vs baseline: 1.2055x; 1.2055x over previous
//
#include <hip/hip_runtime.h>
#include <hip/hip_bf16.h>

#define T_TOTAL 1024
#define BATCH   64
#define HID     512

__device__ __forceinline__ float fast_sigmoid(float x) {
    return 1.f / (1.f + __expf(-x));
}
__device__ __forceinline__ float fast_tanh(float x) {
    float ax = fabsf(x);
    float e  = __expf(-2.f * ax);
    float t  = (1.f - e) / (1.f + e);
    return copysignf(t, x);
}

// ---------------------------------------------------------------------------
// GEMM: C[m,n] = sum_k A[rowg(m),k] * W[n,k] + bias[n]
// A row-major [*, K], W row-major [N, K] (i.e. computes A @ W^T + bias).
// ---------------------------------------------------------------------------
template<int BM, int BN, int TM, int TN>
__global__ __launch_bounds__(256, 2)
void gemm_bt_k(const float* __restrict__ A, const float* __restrict__ W,
               const float* __restrict__ bias, float* __restrict__ C,
               int K, int T, int Tc, int t0, int N)
{
    constexpr int BK = 16;
    constexpr int WSTR = BN + (BN / 32) * 4;
    static_assert(BM / TM == 16 && BN / TN == 16, "256 threads required");
    __shared__ float As[BK][BM + 4];
    __shared__ float Ws[BK][WSTR];

    const int tid = threadIdx.x;
    const int tx  = tid & 15;
    const int ty  = tid >> 4;
    const int m0  = blockIdx.y * BM;
    const int n0  = blockIdx.x * BN;
    const int nA  = tx * TN;
    const int nsw = nA + ((nA >> 5) << 2);

    float acc[TM][TN];
#pragma unroll
    for (int i = 0; i < TM; ++i)
#pragma unroll
        for (int j = 0; j < TN; ++j) acc[i][j] = 0.f;

    for (int k0 = 0; k0 < K; k0 += BK) {
#pragma unroll
        for (int i = 0; i < (BM * BK) / 1024; ++i) {
            int id = tid + (i << 8);
            int m  = id >> 2;
            int kq = (id & 3) << 2;
            int mloc = m0 + m;
            int rowg = (mloc / Tc) * T + t0 + (mloc % Tc);
            const float4 v = *reinterpret_cast<const float4*>(A + (size_t)rowg * K + k0 + kq);
            As[kq + 0][m] = v.x; As[kq + 1][m] = v.y;
            As[kq + 2][m] = v.z; As[kq + 3][m] = v.w;
        }
#pragma unroll
        for (int i = 0; i < (BN * BK) / 1024; ++i) {
            int id = tid + (i << 8);
            int n  = id >> 2;
            int kq = (id & 3) << 2;
            const float4 v = *reinterpret_cast<const float4*>(W + (size_t)(n0 + n) * K + k0 + kq);
            int np = n + ((n >> 5) << 2);
            Ws[kq + 0][np] = v.x; Ws[kq + 1][np] = v.y;
            Ws[kq + 2][np] = v.z; Ws[kq + 3][np] = v.w;
        }
        __syncthreads();
#pragma unroll
        for (int k = 0; k < BK; ++k) {
            float a[TM], b[TN];
#pragma unroll
            for (int i = 0; i < TM; i += 4)
                *reinterpret_cast<float4*>(&a[i]) =
                    *reinterpret_cast<const float4*>(&As[k][ty * TM + i]);
#pragma unroll
            for (int j = 0; j < TN; j += 4)
                *reinterpret_cast<float4*>(&b[j]) =
                    *reinterpret_cast<const float4*>(&Ws[k][nsw + j]);
#pragma unroll
            for (int i = 0; i < TM; ++i)
#pragma unroll
                for (int j = 0; j < TN; ++j)
                    acc[i][j] = fmaf(a[i], b[j], acc[i][j]);
        }
        __syncthreads();
    }
#pragma unroll
    for (int i = 0; i < TM; ++i) {
        const size_t crow = (size_t)(m0 + ty * TM + i) * N + n0 + nA;
#pragma unroll
        for (int j = 0; j < TN; j += 4) {
            float4 bv = *reinterpret_cast<const float4*>(bias + n0 + nA + j);
            float4 v;
            v.x = acc[i][j + 0] + bv.x; v.y = acc[i][j + 1] + bv.y;
            v.z = acc[i][j + 2] + bv.z; v.w = acc[i][j + 3] + bv.w;
            *reinterpret_cast<float4*>(C + crow + j) = v;
        }
    }
}

// ---------------------------------------------------------------------------
// Persistent GRU scan (one T-chunk of one layer) — R10.
// R8 skeleton + PER-WAVE DATAFLOW PIPELINING. Key fact: publisher block os
// of a group publishes exactly dims [os*64,os*64+64) = K-chunk os, and wave
// w consumes exactly K-chunk w. So each wave polls ONLY its own publisher's
// 128 tagged words (R8 protocol, R9's counter-hint reverted — it serialized
// detection and added producer-side waits), stages into its private LDS
// chunk, and MACs immediately — NO block barrier before the MAC. Early
// publishers' MACs overlap the relay tail of late ones. ONE barrier/step.
// part[] double-buffered by step parity (replaces the barrier that
// separated gates' part-reads from next step's part-writes). h_lds slot
// reuse safe: wave w rewrites slot s at step t+2 only after barrier(t+1),
// which follows gates' hp read of slot s at step t. Gates merged with
// reduce (R9's FP-order-identical form). Publish = R8 fire-and-forget.
// ---------------------------------------------------------------------------
__global__ __launch_bounds__(512, 2)
void gru_scan(const float* __restrict__ xg,    // chunk-local [64][Tc][1536]
              const float* __restrict__ w_hh,  // [1536][512]
              const float* __restrict__ b_hh,  // [1536]
              float* __restrict__ y,           // [64][1024][512]
              unsigned long long* __restrict__ hbuf, // [32 grp][2 slot][2 b][512]
              int t0, int Tc, int tagbase)
{
    const int tid = threadIdx.x;
    const int grp = blockIdx.x & 31;      // 8 blocks of a group
    const int os  = blockIdx.x >> 5;      // output slice 0..7
    const int D0  = os << 6;              // 64 h-dims per block
    const int d   = tid & 63;             // lane
    const int kc  = tid >> 6;             // wave index == its K-chunk
    const int bg  = grp << 1;             // 2 batch rows per group

    __shared__ float h_lds[2][1024];      // [slot][b*512 + D]
    __shared__ float part[2][8 * 392];    // [slot][kc][g*128 + b*64 + d]

    // persistent weights: w4[g][j] = w_hh[g*512+D0+d][kc*64 + 4j ..]
    float4 w4[3][16];
#pragma unroll
    for (int g = 0; g < 3; ++g) {
        const float* wr = w_hh + (size_t)(g * 512 + D0 + d) * 512 + kc * 64;
#pragma unroll
        for (int j = 0; j < 16; ++j)
            w4[g][j] = *reinterpret_cast<const float4*>(wr + (j << 2));
    }
    // gate-thread biases (merged reduce+gates)
    float bias_r = 0.f, bias_z = 0.f, bias_n = 0.f;
    if (tid < 128) {
        bias_r = b_hh[       D0 + d];
        bias_z = b_hh[ 512 + D0 + d];
        bias_n = b_hh[1024 + D0 + d];
    }
    const int b_loc = tid >> 6;           // gate threads (tid<128): row 0..1

    for (int tl = 0; tl < Tc; ++tl) {
        const int tg = t0 + tl;
        float* hl = h_lds[tl & 1];
        float* pt = part[tl & 1];

        // gate threads prefetch this step's xg early (hidden behind poll)
        float xr = 0.f, xz = 0.f, xn = 0.f;
        if (tid < 128) {
            const size_t rowo = ((size_t)(bg + b_loc) * Tc + tl) * 1536 + D0 + d;
            xr = xg[rowo];
            xz = xg[rowo + 512];
            xn = xg[rowo + 1024];
        }

        // per-wave staging: wave kc polls ONLY publisher kc's 128 words
        if (tg == 0) {
            hl[      kc * 64 + d] = 0.f;
            hl[512 + kc * 64 + d] = 0.f;
        } else {
            const unsigned long long* hsrc =
                hbuf + (size_t)(grp * 2 + ((tg - 1) & 1)) * 1024 + kc * 64;
            const unsigned int tagexp = (unsigned int)(tagbase + tl - 1);
            unsigned long long v0 = 0, v1 = 0;
            unsigned int pend = 0x3u;
            while (pend) {
                if (pend & 1u)
                    v0 = __hip_atomic_load(hsrc + d,
                            __ATOMIC_RELAXED, __HIP_MEMORY_SCOPE_AGENT);
                if (pend & 2u)
                    v1 = __hip_atomic_load(hsrc + 512 + d,
                            __ATOMIC_RELAXED, __HIP_MEMORY_SCOPE_AGENT);
                if ((pend & 1u) && (unsigned int)(v0 >> 32) == tagexp) {
                    union { unsigned int u; float f; } cv; cv.u = (unsigned int)v0;
                    hl[kc * 64 + d] = cv.f;
                    pend &= ~1u;
                }
                if ((pend & 2u) && (unsigned int)(v1 >> 32) == tagexp) {
                    union { unsigned int u; float f; } cv; cv.u = (unsigned int)v1;
                    hl[512 + kc * 64 + d] = cv.f;
                    pend &= ~2u;
                }
                if (pend) __builtin_amdgcn_s_sleep(1);
            }
        }
        // wave-local LDS RAW: drain lgkmcnt before the broadcast reads
        __builtin_amdgcn_s_waitcnt(0xC07F);   // lgkmcnt(0) only

        // register MAC over this wave's 64-wide K chunk (broadcast reads)
        float acc[3][2];
#pragma unroll
        for (int g = 0; g < 3; ++g) { acc[g][0] = 0.f; acc[g][1] = 0.f; }
        const float* hb = hl + kc * 64;
#pragma unroll
        for (int j = 0; j < 16; ++j) {
            const float4 h0 = *reinterpret_cast<const float4*>(hb + (j << 2));
            const float4 h1 = *reinterpret_cast<const float4*>(hb + 512 + (j << 2));
#pragma unroll
            for (int g = 0; g < 3; ++g) {
                const float4 wv = w4[g][j];
                acc[g][0] = fmaf(wv.x, h0.x, acc[g][0]);
                acc[g][0] = fmaf(wv.y, h0.y, acc[g][0]);
                acc[g][0] = fmaf(wv.z, h0.z, acc[g][0]);
                acc[g][0] = fmaf(wv.w, h0.w, acc[g][0]);
                acc[g][1] = fmaf(wv.x, h1.x, acc[g][1]);
                acc[g][1] = fmaf(wv.y, h1.y, acc[g][1]);
                acc[g][1] = fmaf(wv.z, h1.z, acc[g][1]);
                acc[g][1] = fmaf(wv.w, h1.w, acc[g][1]);
            }
        }
        {
            float* pp = pt + kc * 392 + d;
#pragma unroll
            for (int g = 0; g < 3; ++g) {
                pp[g * 128]      = acc[g][0];
                pp[g * 128 + 64] = acc[g][1];
            }
        }
        __syncthreads();   // the ONLY barrier per step

        // merged reduce + gates + tagged publish (fire-and-forget).
        // FP order identical to R8/R9: bias first, then q ascending.
        if (tid < 128) {
            float sr = bias_r, sz = bias_z, sn = bias_n;
#pragma unroll
            for (int q = 0; q < 8; ++q) {
                sr += pt[q * 392 +       tid];
                sz += pt[q * 392 + 128 + tid];
                sn += pt[q * 392 + 256 + tid];
            }
            const int D = D0 + d;
            const float hp = hl[b_loc * 512 + D];
            const float r  = fast_sigmoid(xr + sr);
            const float z  = fast_sigmoid(xz + sz);
            const float nv = fast_tanh(xn + r * sn);
            const float h  = (1.f - z) * nv + z * hp;
            union { float f; unsigned int u; } cv; cv.f = h;
            const unsigned long long pk =
                ((unsigned long long)(unsigned int)(tagbase + tl) << 32) | cv.u;
            unsigned long long* hdst =
                hbuf + (size_t)(grp * 2 + (tg & 1)) * 1024 + b_loc * 512 + D;
            __hip_atomic_store(hdst, pk, __ATOMIC_RELAXED,
                               __HIP_MEMORY_SCOPE_AGENT);
            y[((size_t)(bg + b_loc) * T_TOTAL + tg) * HID + D] = h;
        }
        // no trailing barrier: h_lds/part are double-buffered by step parity.
    }
}

// ---------------------------------------------------------------------------
extern "C" void kernel_launch(void* const* d_in, const int* in_sizes, int n_in,
                              void* d_out, int out_size, void* d_ws, size_t ws_size,
                              hipStream_t stream)
{
    const float* x       = (const float*)d_in[0];
    const float* w_ih[2] = {(const float*)d_in[1], (const float*)d_in[5]};
    const float* w_hh[2] = {(const float*)d_in[2], (const float*)d_in[6]};
    const float* b_ih[2] = {(const float*)d_in[3], (const float*)d_in[7]};
    const float* b_hh[2] = {(const float*)d_in[4], (const float*)d_in[8]};
    const float* fc_w    = (const float*)d_in[9];
    const float* fc_b    = (const float*)d_in[10];
    float* out = (float*)d_out;

    const size_t Y_BYTES = (size_t)BATCH * T_TOTAL * HID * 4;   // 128 MiB
    const size_t H_BYTES = (size_t)32 * 2 * 2 * 512 * 8;        // 512 KiB (u64)
    int Tc = 256;
    while (Tc > 32) {
        size_t need = (size_t)BATCH * Tc * 1536 * 4 + Y_BYTES + H_BYTES;
        if (need <= ws_size) break;
        Tc >>= 1;
    }

    char* p = (char*)d_ws;
    float* xg_buf = (float*)p;                 p += (size_t)BATCH * Tc * 1536 * 4;
    float* y_buf  = (float*)p;                 p += Y_BYTES;
    unsigned long long* hbuf = (unsigned long long*)p;

    const int nchunks = T_TOTAL / Tc;
    for (int L = 0; L < 2; ++L) {
        const float* A = L ? y_buf : x;
        const int K    = L ? HID : 64;
        for (int c = 0; c < nchunks; ++c) {
            dim3 g1(1536 / 128, (BATCH * Tc) / 128);
            gemm_bt_k<128, 128, 8, 8><<<g1, 256, 0, stream>>>(
                A, w_ih[L], b_ih[L], xg_buf, K, T_TOTAL, Tc, c * Tc, 1536);
            gru_scan<<<256, 512, 0, stream>>>(
                xg_buf, w_hh[L], b_hh[L], y_buf, hbuf,
                c * Tc, Tc, (L << 11) + c * Tc);
        }
    }
    dim3 g2(64 / 64, (BATCH * T_TOTAL) / 128);
    gemm_bt_k<128, 64, 8, 4><<<g2, 256, 0, stream>>>(
        y_buf, fc_w, fc_b, out, HID, BATCH * T_TOTAL, BATCH * T_TOTAL, 0, 64);
}